// Round 1
// baseline (860.211 us; speedup 1.0000x reference)
//
#include <hip/hip_runtime.h>

// GCNConv: out = scatter_add(norm * (x@W^T)[src] -> dst) + selfloop + bias
// N=100000, D=64, E=3200000

__global__ void degree_k(const int* __restrict__ ei, int* __restrict__ deg, int E) {
    int i = blockIdx.x * blockDim.x + threadIdx.x;
    int stride = gridDim.x * blockDim.x;
    for (int e = i; e < E; e += stride) {
        atomicAdd(&deg[ei[E + e]], 1);   // dst row of edge_index
    }
}

__global__ void dis_k(const int* __restrict__ deg, float* __restrict__ dis, int N) {
    int n = blockIdx.x * blockDim.x + threadIdx.x;
    if (n < N) {
        // +1 for the self-loop; deg >= 1 always, so no zero-guard needed
        dis[n] = rsqrtf((float)(deg[n] + 1));
    }
}

// h = x @ W^T : each block does 4 rows, 256 threads = 4 rows x 64 cols.
// W staged in LDS padded [64][65] to avoid stride-64 bank conflicts.
__global__ void transform_k(const float* __restrict__ x, const float* __restrict__ W,
                            float* __restrict__ h, int N) {
    __shared__ float Wl[64][65];
    __shared__ float xl[4][64];
    int t = threadIdx.x;
    for (int i = t; i < 64 * 64; i += 256) Wl[i >> 6][i & 63] = W[i];
    int r = t >> 6;       // row within block (0..3)
    int c = t & 63;       // output column
    long row = (long)blockIdx.x * 4 + r;
    xl[r][c] = (row < N) ? x[row * 64 + c] : 0.0f;
    __syncthreads();
    float acc = 0.0f;
#pragma unroll
    for (int k = 0; k < 64; ++k) acc += xl[r][k] * Wl[c][k];
    if (row < N) h[row * 64 + c] = acc;
}

// out[n][j] = h[n][j] * dis[n]^2 (self-loop, norm = dis*dis) + b[j]
// Also serves as the zero-init of d_out (it's poisoned between replays).
__global__ void init_out_k(const float* __restrict__ h, const float* __restrict__ dis,
                           const float* __restrict__ b, float* __restrict__ out, long total) {
    long i = (long)blockIdx.x * blockDim.x + threadIdx.x;
    long stride = (long)gridDim.x * blockDim.x;
    for (; i < total; i += stride) {
        int n = (int)(i >> 6);
        int j = (int)(i & 63);
        float dn = dis[n];
        out[i] = h[i] * dn * dn + b[j];
    }
}

// One edge per 64-lane group: coalesced 256B gather of h[src], 64 f32 atomics to out[dst].
__global__ void scatter_k(const int* __restrict__ ei, const float* __restrict__ dis,
                          const float* __restrict__ h, float* __restrict__ out, int E) {
    int lane = threadIdx.x & 63;
    int epb = blockDim.x >> 6;                       // edges per block (4)
    long e = (long)blockIdx.x * epb + (threadIdx.x >> 6);
    long estep = (long)gridDim.x * epb;
    for (; e < E; e += estep) {
        int s = ei[e];
        int d = ei[E + e];
        float norm = dis[s] * dis[d];
        float v = h[(long)s * 64 + lane] * norm;
        atomicAdd(&out[(long)d * 64 + lane], v);
    }
}

extern "C" void kernel_launch(void* const* d_in, const int* in_sizes, int n_in,
                              void* d_out, int out_size, void* d_ws, size_t ws_size,
                              hipStream_t stream) {
    const float* x  = (const float*)d_in[0];
    const int*   ei = (const int*)d_in[1];
    const float* W  = (const float*)d_in[2];
    const float* b  = (const float*)d_in[3];
    float* out = (float*)d_out;

    int N = in_sizes[0] / 64;
    int E = in_sizes[1] / 2;

    char* ws = (char*)d_ws;
    int*   deg = (int*)ws;                                // N ints
    float* dis = (float*)(ws + (size_t)N * 4);            // N floats
    float* h   = (float*)(ws + (size_t)N * 8);            // N*64 floats (25.6 MB)

    hipMemsetAsync(deg, 0, (size_t)N * 4, stream);
    degree_k<<<2048, 256, 0, stream>>>(ei, deg, E);
    dis_k<<<(N + 255) / 256, 256, 0, stream>>>(deg, dis, N);
    transform_k<<<(N + 3) / 4, 256, 0, stream>>>(x, W, h, N);
    init_out_k<<<2048, 256, 0, stream>>>(h, dis, b, out, (long)N * 64);
    scatter_k<<<16384, 256, 0, stream>>>(ei, dis, h, out, E);
}

// Round 2
// 671.882 us; speedup vs baseline: 1.2803x; 1.2803x over previous
//
#include <hip/hip_runtime.h>

// GCNConv via CSR-gather (no float atomics):
//   deg -> dis=rsqrt(deg+1) -> exclusive scan -> fill CSR by dst -> h=xW^T ->
//   gather: out[n] = h[n]*dis[n]^2 + b + sum_{e: dst=n} h[src]*dis[src]*dis[n]
// N=100000, D=64, E=3200000

__global__ void degree_k(const int* __restrict__ ei, int* __restrict__ deg, int E) {
    int i = blockIdx.x * blockDim.x + threadIdx.x;
    int stride = gridDim.x * blockDim.x;
    for (int e = i; e < E; e += stride) {
        atomicAdd(&deg[ei[E + e]], 1);   // dst row
    }
}

__global__ void dis_k(const int* __restrict__ deg, float* __restrict__ dis, int N) {
    int n = blockIdx.x * blockDim.x + threadIdx.x;
    if (n < N) dis[n] = rsqrtf((float)(deg[n] + 1));  // +1 self-loop
}

// --- 3-pass exclusive scan of deg[0..N) -> rowptr ---
__global__ void scan1_k(const int* __restrict__ deg, int* __restrict__ rowptr,
                        int* __restrict__ bsum, int N) {
    __shared__ int tmp[256];
    int t = threadIdx.x;
    int g = blockIdx.x * 256 + t;
    int v = (g < N) ? deg[g] : 0;
    tmp[t] = v;
    __syncthreads();
#pragma unroll
    for (int off = 1; off < 256; off <<= 1) {
        int add = (t >= off) ? tmp[t - off] : 0;
        __syncthreads();
        tmp[t] += add;
        __syncthreads();
    }
    if (g < N) rowptr[g] = tmp[t] - v;          // exclusive within block
    if (t == 255) bsum[blockIdx.x] = tmp[255];  // block total
}

__global__ void scan2_k(int* __restrict__ bsum, int nb, int* __restrict__ rowptr,
                        int N, int E) {
    __shared__ int tmp[512];
    int t = threadIdx.x;
    int v = (t < nb) ? bsum[t] : 0;
    tmp[t] = v;
    __syncthreads();
#pragma unroll
    for (int off = 1; off < 512; off <<= 1) {
        int add = (t >= off) ? tmp[t - off] : 0;
        __syncthreads();
        tmp[t] += add;
        __syncthreads();
    }
    if (t < nb) bsum[t] = tmp[t] - v;           // exclusive block offsets
    if (t == 0) rowptr[N] = E;
}

__global__ void scan3_k(int* __restrict__ rowptr, int* __restrict__ cursor,
                        const int* __restrict__ bsum, int N) {
    int g = blockIdx.x * 256 + threadIdx.x;
    if (g < N) {
        int r = rowptr[g] + bsum[blockIdx.x];
        rowptr[g] = r;
        cursor[g] = r;
    }
}

// CSR fill: ent[pos] = src for each edge, pos allocated per-dst via int atomics.
__global__ void fill_k(const int* __restrict__ ei, int* __restrict__ cursor,
                       int* __restrict__ ent, int E) {
    int i = blockIdx.x * blockDim.x + threadIdx.x;
    int stride = gridDim.x * blockDim.x;
    for (int e = i; e < E; e += stride) {
        int s = ei[e];
        int d = ei[E + e];
        int pos = atomicAdd(&cursor[d], 1);
        ent[pos] = s;
    }
}

// h = x @ W^T : 4 rows/block, W staged in LDS padded [64][65].
__global__ void transform_k(const float* __restrict__ x, const float* __restrict__ W,
                            float* __restrict__ h, int N) {
    __shared__ float Wl[64][65];
    __shared__ float xl[4][64];
    int t = threadIdx.x;
    for (int i = t; i < 64 * 64; i += 256) Wl[i >> 6][i & 63] = W[i];
    int r = t >> 6;
    int c = t & 63;
    int row = blockIdx.x * 4 + r;
    xl[r][c] = (row < N) ? x[row * 64 + c] : 0.0f;
    __syncthreads();
    float acc = 0.0f;
#pragma unroll
    for (int k = 0; k < 64; ++k) acc += xl[r][k] * Wl[c][k];
    if (row < N) h[row * 64 + c] = acc;
}

// One wave per node: registers accumulate, single coalesced write. No atomics.
__global__ void gather_k(const int* __restrict__ rowptr, const int* __restrict__ ent,
                         const float* __restrict__ dis, const float* __restrict__ h,
                         const float* __restrict__ b, float* __restrict__ out, int N) {
    int lane = threadIdx.x & 63;
    int wpb = blockDim.x >> 6;
    int n = blockIdx.x * wpb + (threadIdx.x >> 6);
    if (n >= N) return;
    float dn = dis[n];
    float acc = h[n * 64 + lane] * dn * dn + b[lane];  // self-loop + bias (also inits out)
    int beg = rowptr[n];
    int end = rowptr[n + 1];
    for (int i = beg; i < end; i += 64) {
        int m = end - i;
        if (m > 64) m = 64;
        int src = 0;
        float nrm = 0.0f;
        if (lane < m) {
            src = ent[i + lane];            // coalesced chunk of edge sources
            nrm = dis[src] * dn;            // parallel random read, L2-resident
        }
        for (int j = 0; j < m; ++j) {
            int s = __shfl(src, j, 64);
            float w = __shfl(nrm, j, 64);
            acc += h[s * 64 + lane] * w;    // coalesced 256B row gather, L3-resident
        }
    }
    out[n * 64 + lane] = acc;
}

extern "C" void kernel_launch(void* const* d_in, const int* in_sizes, int n_in,
                              void* d_out, int out_size, void* d_ws, size_t ws_size,
                              hipStream_t stream) {
    const float* x  = (const float*)d_in[0];
    const int*   ei = (const int*)d_in[1];
    const float* W  = (const float*)d_in[2];
    const float* b  = (const float*)d_in[3];
    float* out = (float*)d_out;

    int N = in_sizes[0] / 64;
    int E = in_sizes[1] / 2;
    int nb = (N + 255) / 256;   // scan blocks (391)

    char* ws = (char*)d_ws;
    size_t off = 0;
    auto alloc = [&](size_t bytes) { char* p = ws + off; off += (bytes + 255) & ~(size_t)255; return p; };
    int*   deg    = (int*)alloc((size_t)N * 4);
    float* dis    = (float*)alloc((size_t)N * 4);
    int*   rowptr = (int*)alloc((size_t)(N + 1) * 4);
    int*   cursor = (int*)alloc((size_t)N * 4);
    int*   bsum   = (int*)alloc(512 * 4);
    int*   ent    = (int*)alloc((size_t)E * 4);
    float* h      = (float*)alloc((size_t)N * 64 * 4);

    hipMemsetAsync(deg, 0, (size_t)N * 4, stream);
    degree_k<<<2048, 256, 0, stream>>>(ei, deg, E);
    dis_k<<<(N + 255) / 256, 256, 0, stream>>>(deg, dis, N);
    scan1_k<<<nb, 256, 0, stream>>>(deg, rowptr, bsum, N);
    scan2_k<<<1, 512, 0, stream>>>(bsum, nb, rowptr, N, E);
    scan3_k<<<nb, 256, 0, stream>>>(rowptr, cursor, bsum, N);
    fill_k<<<2048, 256, 0, stream>>>(ei, cursor, ent, E);
    transform_k<<<(N + 3) / 4, 256, 0, stream>>>(x, W, h, N);
    gather_k<<<(N + 3) / 4, 256, 0, stream>>>(rowptr, ent, dis, h, b, out, N);
}